// Round 8
// baseline (102.257 us; speedup 1.0000x reference)
//
#include <hip/hip_runtime.h>

// Problem constants
#define NBATCH 8
#define TSEQ 2048
#define EDIM 1024
#define HDIM 64
#define NROW (NBATCH * TSEQ)  // 16384

typedef unsigned short u16;
typedef __attribute__((ext_vector_type(8))) short bf16x8;   // 8 bf16 (4 VGPRs)
typedef __attribute__((ext_vector_type(8))) short short8;   // 16B load vehicle
typedef __attribute__((ext_vector_type(4))) float f32x4;

// fp32 -> bf16 round-to-nearest-even (bit pattern)
__device__ __forceinline__ u16 f2b(float x) {
  unsigned int u = __float_as_uint(x);
  unsigned int r = (u + 0x7fffu + ((u >> 16) & 1u)) >> 16;
  return (u16)r;
}
__device__ __forceinline__ float b2f(u16 h) {
  return __uint_as_float(((unsigned int)h) << 16);
}

// ---------------------------------------------------------------------------
// Kernel 0: W [1024][64] fp32 -> Wt [192][1024] bf16 (transposed), via LDS.
// ---------------------------------------------------------------------------
__global__ __launch_bounds__(256) void wt_kernel(
    const float* __restrict__ Wq, const float* __restrict__ Wk,
    const float* __restrict__ Wv, u16* __restrict__ Wt) {
  __shared__ float s[64][65];
  const int o = blockIdx.x >> 4, et = blockIdx.x & 15;
  const float* W = (o == 0) ? Wq : (o == 1) ? Wk : Wv;
  const int t = threadIdx.x;
  const int e0 = et * 64;
#pragma unroll
  for (int i = 0; i < 16; i++) {
    int e = i * 4 + (t >> 6), h = t & 63;
    s[e][h] = W[(size_t)(e0 + e) * HDIM + h];
  }
  __syncthreads();
#pragma unroll
  for (int j = 0; j < 16; j++) {
    int h = j * 4 + (t >> 6), e = t & 63;
    Wt[(size_t)(o * 64 + h) * EDIM + e0 + e] = f2b(s[e][h]);
  }
}

// ---------------------------------------------------------------------------
// Kernel 1: QKV projection — pure-register pipeline, NO LDS, NO barriers.
// Grid 512 blocks (32 t-rows) x 256 thr; wave w owns h-rows w*48..+47
// (3 A-tiles) x 2 t-colsets -> 6 C-tiles, acc 24 VGPR.
// Per 64-e stage: lane gathers its X B-frags straight from global (block's
// 128 KB X slice is L1/L2-cached across the 4 waves), W^T A-frags from
// global (L2-hot, 384 KB total). Ping-pong register sets (X 2x32, W 2x24
// VGPR), stage k+1 issued before compute of stage k, sched_barrier(0) pins
// issues above compute (the r6-attn pattern that beat load-sinking).
// Register-dest loads cross freely -- no vmcnt drains anywhere.
// MFMA D[h][t]: A=W^T rows, B=X^T cols; k = kc*32+g*8+j; C/D col(li)=t,
// row(g*4+r)=h. Q pre-scaled by 0.125*log2(e) for exp2 in attention.
// ---------------------------------------------------------------------------
#define PISSUE_X(XS, E0)                                                   \
  do {                                                                     \
    _Pragma("unroll") for (int cs = 0; cs < 2; cs++) {                     \
      _Pragma("unroll") for (int kc = 0; kc < 2; kc++) {                   \
        const float* xp_ = Xb + (size_t)(cs * 16) * EDIM + (E0) + kc * 32; \
        XS[(cs * 2 + kc) * 2 + 0] = *(const float4*)(xp_);                 \
        XS[(cs * 2 + kc) * 2 + 1] = *(const float4*)(xp_ + 4);             \
      }                                                                    \
    }                                                                      \
  } while (0)

#define PISSUE_W(WS, E0)                                                   \
  do {                                                                     \
    _Pragma("unroll") for (int mt = 0; mt < 3; mt++) {                     \
      _Pragma("unroll") for (int kc = 0; kc < 2; kc++) {                   \
        WS[mt * 2 + kc] =                                                  \
            *(const bf16x8*)(Wb + (size_t)(mt * 16) * EDIM + (E0) + kc * 32); \
      }                                                                    \
    }                                                                      \
  } while (0)

#define PCOMPUTE(XS, WS)                                                   \
  do {                                                                     \
    bf16x8 bfr_[4];                                                        \
    _Pragma("unroll") for (int i = 0; i < 4; i++) {                        \
      const float4 f0_ = XS[i * 2 + 0];                                    \
      const float4 f1_ = XS[i * 2 + 1];                                    \
      bfr_[i] = (bf16x8){(short)f2b(f0_.x), (short)f2b(f0_.y),             \
                         (short)f2b(f0_.z), (short)f2b(f0_.w),             \
                         (short)f2b(f1_.x), (short)f2b(f1_.y),             \
                         (short)f2b(f1_.z), (short)f2b(f1_.w)};            \
    }                                                                      \
    _Pragma("unroll") for (int mt = 0; mt < 3; mt++) {                     \
      _Pragma("unroll") for (int kc = 0; kc < 2; kc++) {                   \
        _Pragma("unroll") for (int cs = 0; cs < 2; cs++) {                 \
          acc[mt * 2 + cs] = __builtin_amdgcn_mfma_f32_16x16x32_bf16(      \
              WS[mt * 2 + kc], bfr_[cs * 2 + kc], acc[mt * 2 + cs], 0, 0, 0); \
        }                                                                  \
      }                                                                    \
    }                                                                      \
  } while (0)

__global__ __launch_bounds__(256, 2) void proj_mfma(
    const float* __restrict__ X, const u16* __restrict__ Wt,
    const float* __restrict__ bq, const float* __restrict__ bk,
    const float* __restrict__ bv,
    u16* __restrict__ Qb, u16* __restrict__ Kb, u16* __restrict__ Vt) {
  const int tid = threadIdx.x;
  const int w = tid >> 6, l = tid & 63;
  const int g = l >> 4, li = l & 15;
  const long bt0 = (long)blockIdx.x * 32;

  const float* Xb = X + (bt0 + li) * EDIM + g * 8;
  const u16* Wb = Wt + (size_t)(w * 48 + li) * EDIM + g * 8;

  f32x4 acc[6];  // [mt][cs]
#pragma unroll
  for (int i = 0; i < 6; i++) acc[i] = (f32x4)0.f;

  float4 xA[8], xB[8];
  bf16x8 wA[6], wB[6];

  PISSUE_X(xA, 0);
  PISSUE_W(wA, 0);
#pragma unroll
  for (int ks = 0; ks < 16; ks += 2) {
    PISSUE_X(xB, (ks + 1) * 64);
    PISSUE_W(wB, (ks + 1) * 64);
    __builtin_amdgcn_sched_barrier(0);
    PCOMPUTE(xA, wA);
    if (ks + 2 < 16) {
      PISSUE_X(xA, (ks + 2) * 64);
      PISSUE_W(wA, (ks + 2) * 64);
    }
    __builtin_amdgcn_sched_barrier(0);
    PCOMPUTE(xB, wB);
  }

  // epilogue: lane holds out^T[n0 = w*48+mt*16+g*4 (+r)][t = bt0+cs*16+li]
  const float qscale = 0.18033688011112042f;  // 0.125 * log2(e)
#pragma unroll
  for (int cs = 0; cs < 2; cs++) {
    const long tg = bt0 + cs * 16 + li;
    const int b = (int)(tg >> 11), tl = (int)(tg & 2047);
#pragma unroll
    for (int mt = 0; mt < 3; mt++) {
      const int n0 = w * 48 + mt * 16 + g * 4;
      const int o = n0 >> 6;
      const int h0 = n0 & 63;
      const float* bias = (o == 0) ? bq : (o == 1) ? bk : bv;
      const float4 bb = *(const float4*)&bias[h0];
      const f32x4 a = acc[mt * 2 + cs];
      float v0 = a.x + bb.x, v1 = a.y + bb.y;
      float v2 = a.z + bb.z, v3 = a.w + bb.w;
      if (o == 0) {
        v0 *= qscale; v1 *= qscale; v2 *= qscale; v3 *= qscale;
        uint2 pk = make_uint2((unsigned)f2b(v0) | ((unsigned)f2b(v1) << 16),
                              (unsigned)f2b(v2) | ((unsigned)f2b(v3) << 16));
        *(uint2*)&Qb[tg * HDIM + h0] = pk;
      } else if (o == 1) {
        uint2 pk = make_uint2((unsigned)f2b(v0) | ((unsigned)f2b(v1) << 16),
                              (unsigned)f2b(v2) | ((unsigned)f2b(v3) << 16));
        *(uint2*)&Kb[tg * HDIM + h0] = pk;
      } else {
        Vt[(size_t)(b * 64 + h0 + 0) * TSEQ + tl] = f2b(v0);
        Vt[(size_t)(b * 64 + h0 + 1) * TSEQ + tl] = f2b(v1);
        Vt[(size_t)(b * 64 + h0 + 2) * TSEQ + tl] = f2b(v2);
        Vt[(size_t)(b * 64 + h0 + 3) * TSEQ + tl] = f2b(v3);
      }
    }
  }
}

// ---------------------------------------------------------------------------
// Kernel 2a: per-64-chunk V sums. Grid 256 = (b,c); 64 thr; thread h sums
// its contiguous 128 B run of Vt.
// ---------------------------------------------------------------------------
__global__ __launch_bounds__(64) void css_part(const u16* __restrict__ Vt,
                                               float* __restrict__ CS) {
  const int b = blockIdx.x >> 5, c = blockIdx.x & 31, h = threadIdx.x;
  const u16* vp = Vt + ((size_t)b * 64 + h) * TSEQ + c * 64;
  float s = 0.f;
#pragma unroll
  for (int i = 0; i < 8; i++) {
    const short8 a = *(const short8*)(vp + i * 8);
    s += b2f((u16)a[0]) + b2f((u16)a[1]) + b2f((u16)a[2]) + b2f((u16)a[3]) +
         b2f((u16)a[4]) + b2f((u16)a[5]) + b2f((u16)a[6]) + b2f((u16)a[7]);
  }
  CS[((size_t)b * 32 + c) * 64 + h] = s;
}

// ---------------------------------------------------------------------------
// Kernel 2b: suffix scan. CSS[b][c][h] = sum_{k>=c*64} V[b][k][h], c=0..32.
// 8 blocks x 64 thr; 32 loads fully unrolled (independent, L2-hot).
// ---------------------------------------------------------------------------
__global__ __launch_bounds__(64) void css_scan(const float* __restrict__ CS,
                                               float* __restrict__ CSS) {
  const int b = blockIdx.x, h = threadIdx.x;
  float v[32];
#pragma unroll
  for (int c = 0; c < 32; c++) v[c] = CS[((size_t)b * 32 + c) * 64 + h];
  float S = 0.f;
  CSS[((size_t)b * 33 + 32) * 64 + h] = 0.f;
#pragma unroll
  for (int c = 31; c >= 0; c--) {
    S += v[c];
    CSS[((size_t)b * 33 + c) * 64 + h] = S;
  }
}

// ---------------------------------------------------------------------------
// Kernel 3: MFMA attention (unchanged from r6/r7 — proven).
// ---------------------------------------------------------------------------
#define ISSUE_K(K0A, K1A, KO)                                              \
  do {                                                                     \
    _Pragma("unroll") for (int n = 0; n < 4; n++) {                        \
      const u16* kp_ = Kbb + (size_t)((KO) + n * 16 + li) * HDIM + g * 8;  \
      K0A[n] = *(const bf16x8*)(kp_);                                      \
      K1A[n] = *(const bf16x8*)(kp_ + 32);                                 \
    }                                                                      \
  } while (0)

#define ISSUE_V(KO)                                                        \
  do {                                                                     \
    _Pragma("unroll") for (int n = 0; n < 4; n++) {                        \
      const u16* vp_ = Vtb + (size_t)(n * 16 + li) * TSEQ + (KO) + g * 8;  \
      vf0[n] = *(const bf16x8*)(vp_);                                      \
      vf1[n] = *(const bf16x8*)(vp_ + 32);                                 \
    }                                                                      \
  } while (0)

#define COMPUTE_TILE(K0A, K1A, KO)                                         \
  do {                                                                     \
    f32x4 s_[4];                                                           \
    _Pragma("unroll") for (int n = 0; n < 4; n++) {                        \
      s_[n] = (f32x4)0.f;                                                  \
      s_[n] = __builtin_amdgcn_mfma_f32_16x16x32_bf16(qa[0], K0A[n], s_[n], 0, 0, 0); \
      s_[n] = __builtin_amdgcn_mfma_f32_16x16x32_bf16(qa[1], K1A[n], s_[n], 0, 0, 0); \
    }                                                                      \
    _Pragma("unroll") for (int r = 0; r < 4; r++) {                        \
      const int qi_ = qi0 + r;                                             \
      float p0_ = ((KO) + 0 + li <= qi_) ? exp2f(s_[0][r]) : 1.0f;         \
      float p1_ = ((KO) + 16 + li <= qi_) ? exp2f(s_[1][r]) : 1.0f;        \
      float p2_ = ((KO) + 32 + li <= qi_) ? exp2f(s_[2][r]) : 1.0f;        \
      float p3_ = ((KO) + 48 + li <= qi_) ? exp2f(s_[3][r]) : 1.0f;        \
      zacc[r] += (p0_ + p1_) + (p2_ + p3_);                                \
      sp[w][g * 4 + r][li + 0] = p0_;                                      \
      sp[w][g * 4 + r][li + 16] = p1_;                                     \
      sp[w][g * 4 + r][li + 32] = p2_;                                     \
      sp[w][g * 4 + r][li + 48] = p3_;                                     \
    }                                                                      \
    bf16x8 pa0_, pa1_;                                                     \
    {                                                                      \
      const float* pr_ = &sp[w][li][g * 8];                                \
      const float4 a_ = *(const float4*)(pr_);                             \
      const float4 b_ = *(const float4*)(pr_ + 4);                         \
      pa0_ = (bf16x8){(short)f2b(a_.x), (short)f2b(a_.y), (short)f2b(a_.z),\
                      (short)f2b(a_.w), (short)f2b(b_.x), (short)f2b(b_.y),\
                      (short)f2b(b_.z), (short)f2b(b_.w)};                 \
      const float4 c_ = *(const float4*)(pr_ + 32);                        \
      const float4 d_ = *(const float4*)(pr_ + 36);                        \
      pa1_ = (bf16x8){(short)f2b(c_.x), (short)f2b(c_.y), (short)f2b(c_.z),\
                      (short)f2b(c_.w), (short)f2b(d_.x), (short)f2b(d_.y),\
                      (short)f2b(d_.z), (short)f2b(d_.w)};                 \
    }                                                                      \
    _Pragma("unroll") for (int nt = 0; nt < 4; nt++) {                     \
      oacc[nt] = __builtin_amdgcn_mfma_f32_16x16x32_bf16(pa0_, vf0[nt], oacc[nt], 0, 0, 0); \
      oacc[nt] = __builtin_amdgcn_mfma_f32_16x16x32_bf16(pa1_, vf1[nt], oacc[nt], 0, 0, 0); \
    }                                                                      \
  } while (0)

__global__ __launch_bounds__(256, 2) void attn_mfma(
    const u16* __restrict__ Qb, const u16* __restrict__ Kb,
    const u16* __restrict__ Vt, const float* __restrict__ CSS,
    float* __restrict__ Out) {
  __shared__ float sp[4][16][68];  // wave-private P buffer / merge buffer

  const int tid = threadIdx.x;
  const int w = tid >> 6, l = tid & 63;
  const int g = l >> 4, li = l & 15;

  const int gb = blockIdx.x & 7;    // batch -> XCD pin (bid % 8 round-robin)
  const int j = blockIdx.x >> 3;    // 0..127
  const int gr = 127 - j;           // longest-first
  const int q0 = gr * 16;

  const size_t qbase = ((size_t)gb * TSEQ + q0 + li) * HDIM;
  bf16x8 qa[2];
  qa[0] = *(const bf16x8*)(Qb + qbase + g * 8);
  qa[1] = *(const bf16x8*)(Qb + qbase + g * 8 + 32);

  float zacc[4];
  f32x4 oacc[4];
#pragma unroll
  for (int r = 0; r < 4; r++) zacc[r] = 0.f;
#pragma unroll
  for (int nt = 0; nt < 4; nt++) oacc[nt] = (f32x4)0.f;

  const int qi0 = q0 + g * 4;
  const int nt = gr / 4 + 1;  // tiles for this block's rows
  const u16* Kbb = Kb + (size_t)gb * TSEQ * HDIM;
  const u16* Vtb = Vt + (size_t)gb * 64 * TSEQ;

  bf16x8 kA0[4], kA1[4], kB0[4], kB1[4], vf0[4], vf1[4];

  int kt = w;
  if (kt < nt) {
    ISSUE_K(kA0, kA1, kt * 64);
    while (true) {
      ISSUE_V(kt * 64);
      if (kt + 4 < nt) ISSUE_K(kB0, kB1, (kt + 4) * 64);
      __builtin_amdgcn_sched_barrier(0);
      COMPUTE_TILE(kA0, kA1, kt * 64);
      kt += 4;
      if (kt >= nt) break;
      ISSUE_V(kt * 64);
      if (kt + 4 < nt) ISSUE_K(kA0, kA1, (kt + 4) * 64);
      __builtin_amdgcn_sched_barrier(0);
      COMPUTE_TILE(kB0, kB1, kt * 64);
      kt += 4;
      if (kt >= nt) break;
    }
  }

  // per-row Z: reduce zacc over the 16 li lanes
#pragma unroll
  for (int r = 0; r < 4; r++) {
#pragma unroll
    for (int d = 1; d < 16; d <<= 1) zacc[r] += __shfl_xor(zacc[r], d, 64);
  }

  // publish partials into this wave's own sp region
#pragma unroll
  for (int n = 0; n < 4; n++) {
#pragma unroll
    for (int r = 0; r < 4; r++) sp[w][g * 4 + r][n * 16 + li] = oacc[n][r];
  }
  if (li == 0) {
#pragma unroll
    for (int r = 0; r < 4; r++) sp[w][g * 4 + r][64] = zacc[r];
  }
  __syncthreads();

  // merge 4 wave-partials + tail correction + normalize
  const float tailz = (float)(TSEQ - nt * 64);
  const float tailv = CSS[((size_t)gb * 33 + nt) * 64 + l];
#pragma unroll
  for (int r = 0; r < 4; r++) {
    const int q = w * 4 + r;
    const int qi = q0 + q;
    float a = ((sp[0][q][l] + sp[1][q][l]) + (sp[2][q][l] + sp[3][q][l]));
    float zz = ((sp[0][q][64] + sp[1][q][64]) + (sp[2][q][64] + sp[3][q][64]));
    zz += tailz;
    a += tailv;
    Out[((size_t)gb * TSEQ + qi) * HDIM + l] = a / zz;
  }
}

// ---------------------------------------------------------------------------
extern "C" void kernel_launch(void* const* d_in, const int* in_sizes, int n_in,
                              void* d_out, int out_size, void* d_ws, size_t ws_size,
                              hipStream_t stream) {
  const float* X  = (const float*)d_in[0];
  const float* Wq = (const float*)d_in[1];
  const float* bq = (const float*)d_in[2];
  const float* Wk = (const float*)d_in[3];
  const float* bk = (const float*)d_in[4];
  const float* Wv = (const float*)d_in[5];
  const float* bv = (const float*)d_in[6];
  float* out = (float*)d_out;

  // workspace (~6.9 MB)
  char* ws = (char*)d_ws;
  u16*   Qb  = (u16*)(ws);                   // 2 MB  bf16 [NROW][64] (pre-scaled)
  u16*   Kb  = (u16*)(ws + 2097152);         // 2 MB  bf16 [NROW][64]
  u16*   Vt  = (u16*)(ws + 4194304);         // 2 MB  bf16 [B][64][T]
  u16*   Wt  = (u16*)(ws + 6291456);         // 384 KB bf16 [192][1024]
  float* CSS = (float*)(ws + 6684672);       // 67.6 KB fp32 [B][33][64]
  float* CS  = (float*)(ws + 6752256);       // 64 KB  fp32 [B][32][64]

  wt_kernel<<<48, 256, 0, stream>>>(Wq, Wk, Wv, Wt);
  proj_mfma<<<NROW / 32, 256, 0, stream>>>(X, Wt, bq, bk, bv, Qb, Kb, Vt);
  css_part<<<NBATCH * 32, 64, 0, stream>>>(Vt, CS);
  css_scan<<<NBATCH, 64, 0, stream>>>(CS, CSS);
  attn_mfma<<<NROW / 16, 256, 0, stream>>>(Qb, Kb, Vt, CSS, out);
}

// Round 9
// 79.289 us; speedup vs baseline: 1.2897x; 1.2897x over previous
//
#include <hip/hip_runtime.h>

// Problem constants
#define NBATCH 8
#define TSEQ 2048
#define EDIM 1024
#define HDIM 64
#define NROW (NBATCH * TSEQ)  // 16384

typedef unsigned short u16;
typedef __attribute__((ext_vector_type(8))) short bf16x8;   // 8 bf16 (4 VGPRs)
typedef __attribute__((ext_vector_type(8))) short short8;   // 16B load vehicle
typedef __attribute__((ext_vector_type(4))) float f32x4;

typedef unsigned int uint_as1 __attribute__((address_space(1)));
typedef unsigned int uint_as3 __attribute__((address_space(3)));

// fp32 -> bf16 round-to-nearest-even (bit pattern)
__device__ __forceinline__ u16 f2b(float x) {
  unsigned int u = __float_as_uint(x);
  unsigned int r = (u + 0x7fffu + ((u >> 16) & 1u)) >> 16;
  return (u16)r;
}
__device__ __forceinline__ float b2f(u16 h) {
  return __uint_as_float(((unsigned int)h) << 16);
}
// async global->LDS, 16 B per lane (dest = wave base + lane*16, linear)
__device__ __forceinline__ void gl16(const void* g, void* l) {
  __builtin_amdgcn_global_load_lds((const uint_as1*)g, (uint_as3*)l, 16, 0, 0);
}

// ---------------------------------------------------------------------------
// Kernel 0: W [1024][64] fp32 -> Wt [192][1024] bf16 (transposed), via LDS.
// ---------------------------------------------------------------------------
__global__ __launch_bounds__(256) void wt_kernel(
    const float* __restrict__ Wq, const float* __restrict__ Wk,
    const float* __restrict__ Wv, u16* __restrict__ Wt) {
  __shared__ float s[64][65];
  const int o = blockIdx.x >> 4, et = blockIdx.x & 15;
  const float* W = (o == 0) ? Wq : (o == 1) ? Wk : Wv;
  const int t = threadIdx.x;
  const int e0 = et * 64;
#pragma unroll
  for (int i = 0; i < 16; i++) {
    int e = i * 4 + (t >> 6), h = t & 63;
    s[e][h] = W[(size_t)(e0 + e) * HDIM + h];
  }
  __syncthreads();
#pragma unroll
  for (int j = 0; j < 16; j++) {
    int h = j * 4 + (t >> 6), e = t & 63;
    Wt[(size_t)(o * 64 + h) * EDIM + e0 + e] = f2b(s[e][h]);
  }
}

// ---------------------------------------------------------------------------
// Kernel 1: QKV projection, double-buffered gl16 LDS pipeline with COUNTED
// vmcnt (T4): the per-iteration wait is vmcnt(8) -- only stage-k's 8 gl16s
// (issued one full iteration ago, covered by compute+transfer overlap) --
// and raw s_barrier instead of __syncthreads, so stage-k+1's loads stay in
// flight across the barrier (r7's __syncthreads drained the just-issued
// prefetch every iteration: ~2400cy exposed/stage).
// Geometry unchanged from r7: 512 blocks x 256 thr; 32t x 192h per block;
// BK=64, 16 stages; LDS 2x(8KB X + 24KB W) = 64KB -> 2 blocks/CU.
// Pre-swizzled global source (slot = c ^ (row&7)); reads apply same XOR.
// MFMA D[h][t]: A=W^T rows, B=X^T cols; C/D col(li)=t, row(g*4+r)=h.
// Q pre-scaled by 0.125*log2(e) for exp2 in attention.
// ---------------------------------------------------------------------------
#define XBUF (32 * 256)    // 8 KB per buffer
#define WBUF (192 * 128)   // 24 KB per buffer

__global__ __launch_bounds__(256, 2) void proj_mfma(
    const float* __restrict__ X, const u16* __restrict__ Wt,
    const float* __restrict__ bq, const float* __restrict__ bk,
    const float* __restrict__ bv,
    u16* __restrict__ Qb, u16* __restrict__ Kb, u16* __restrict__ Vt) {
  __shared__ __align__(16) char sx[2 * XBUF];  // [buf][32 t][16 gran] fp32
  __shared__ __align__(16) char sw[2 * WBUF];  // [buf][192 h][8 gran] bf16

  const int tid = threadIdx.x;
  const int w = tid >> 6, l = tid & 63;
  const int g = l >> 4, li = l & 15;
  const long bt0 = (long)blockIdx.x * 32;

  // X staging: 512 granules/buffer, 2 per thread (rows tid>>4 and 16+tid>>4)
  const int xr = tid >> 4, xc = tid & 15;
  const float* xsrc0 = X + (bt0 + xr) * EDIM + ((xc ^ (xr & 7)) * 4);
  const float* xsrc1 = X + (bt0 + 16 + xr) * EDIM + ((xc ^ (xr & 7)) * 4);

  f32x4 acc[6];  // [mt][cs]
#pragma unroll
  for (int i = 0; i < 6; i++) acc[i] = (f32x4)0.f;

  // 8 gl16 per WAVE per stage (2 X + 6 W) -> vmcnt counting unit
#define STAGE(BUF, E0)                                                       \
  do {                                                                       \
    gl16(xsrc0 + (E0), sx + (BUF)*XBUF + tid * 16);                          \
    gl16(xsrc1 + (E0), sx + (BUF)*XBUF + (tid + 256) * 16);                  \
    _Pragma("unroll") for (int j = 0; j < 6; j++) {                          \
      const int L = j * 256 + tid;                                           \
      const int r = L >> 3, c = L & 7;                                       \
      gl16(Wt + (size_t)r * EDIM + (E0) + ((c ^ (r & 7)) * 8),               \
           sw + (BUF)*WBUF + L * 16);                                        \
    }                                                                        \
  } while (0)

  STAGE(0, 0);
  asm volatile("s_waitcnt vmcnt(0)" ::: "memory");
  __builtin_amdgcn_sched_barrier(0);
  __builtin_amdgcn_s_barrier();
  __builtin_amdgcn_sched_barrier(0);

  for (int ks = 0; ks < 16; ks++) {
    const int buf = ks & 1;
    if (ks < 15) STAGE(buf ^ 1, (ks + 1) * 64);
    __builtin_amdgcn_sched_barrier(0);
    // wait ONLY for stage-k's 8 gl16s (next stage's 8 remain in flight)
    if (ks < 15) {
      asm volatile("s_waitcnt vmcnt(8)" ::: "memory");
    } else {
      asm volatile("s_waitcnt vmcnt(0)" ::: "memory");
    }
    __builtin_amdgcn_sched_barrier(0);
    __builtin_amdgcn_s_barrier();  // all waves' stage-k data in LDS
    __builtin_amdgcn_sched_barrier(0);

    const char* xb = sx + buf * XBUF;
    const char* wb = sw + buf * WBUF;
    // B-frags (X^T): colset cs -> t-row cs*16+li; e-granules kc*8+g*2, +1
    bf16x8 bfr[2][2];
#pragma unroll
    for (int cs = 0; cs < 2; cs++) {
      const int row = cs * 16 + li;
#pragma unroll
      for (int kc = 0; kc < 2; kc++) {
        const int G0 = kc * 8 + g * 2;
        const float4 f0 = *(const float4*)(xb + row * 256 + ((G0 ^ (row & 7)) * 16));
        const float4 f1 = *(const float4*)(xb + row * 256 + (((G0 + 1) ^ (row & 7)) * 16));
        bfr[cs][kc] = (bf16x8){(short)f2b(f0.x), (short)f2b(f0.y),
                               (short)f2b(f0.z), (short)f2b(f0.w),
                               (short)f2b(f1.x), (short)f2b(f1.y),
                               (short)f2b(f1.z), (short)f2b(f1.w)};
      }
    }
    // A-frags (W^T rows) + MFMA
#pragma unroll
    for (int mt = 0; mt < 3; mt++) {
      const int row = w * 48 + mt * 16 + li;
#pragma unroll
      for (int kc = 0; kc < 2; kc++) {
        const int G = kc * 4 + g;
        const bf16x8 af = *(const bf16x8*)(wb + row * 128 + ((G ^ (row & 7)) * 16));
        acc[mt * 2 + 0] = __builtin_amdgcn_mfma_f32_16x16x32_bf16(
            af, bfr[0][kc], acc[mt * 2 + 0], 0, 0, 0);
        acc[mt * 2 + 1] = __builtin_amdgcn_mfma_f32_16x16x32_bf16(
            af, bfr[1][kc], acc[mt * 2 + 1], 0, 0, 0);
      }
    }
    __builtin_amdgcn_sched_barrier(0);
    __builtin_amdgcn_s_barrier();  // reads of buf done before next overwrite
    __builtin_amdgcn_sched_barrier(0);
  }
#undef STAGE

  // epilogue: lane holds out^T[n0 = w*48+mt*16+g*4 (+r)][t = bt0+cs*16+li]
  const float qscale = 0.18033688011112042f;  // 0.125 * log2(e)
#pragma unroll
  for (int cs = 0; cs < 2; cs++) {
    const long tg = bt0 + cs * 16 + li;
    const int b = (int)(tg >> 11), tl = (int)(tg & 2047);
#pragma unroll
    for (int mt = 0; mt < 3; mt++) {
      const int n0 = w * 48 + mt * 16 + g * 4;
      const int o = n0 >> 6;
      const int h0 = n0 & 63;
      const float* bias = (o == 0) ? bq : (o == 1) ? bk : bv;
      const float4 bb = *(const float4*)&bias[h0];
      const f32x4 a = acc[mt * 2 + cs];
      float v0 = a.x + bb.x, v1 = a.y + bb.y;
      float v2 = a.z + bb.z, v3 = a.w + bb.w;
      if (o == 0) {
        v0 *= qscale; v1 *= qscale; v2 *= qscale; v3 *= qscale;
        uint2 pk = make_uint2((unsigned)f2b(v0) | ((unsigned)f2b(v1) << 16),
                              (unsigned)f2b(v2) | ((unsigned)f2b(v3) << 16));
        *(uint2*)&Qb[tg * HDIM + h0] = pk;
      } else if (o == 1) {
        uint2 pk = make_uint2((unsigned)f2b(v0) | ((unsigned)f2b(v1) << 16),
                              (unsigned)f2b(v2) | ((unsigned)f2b(v3) << 16));
        *(uint2*)&Kb[tg * HDIM + h0] = pk;
      } else {
        Vt[(size_t)(b * 64 + h0 + 0) * TSEQ + tl] = f2b(v0);
        Vt[(size_t)(b * 64 + h0 + 1) * TSEQ + tl] = f2b(v1);
        Vt[(size_t)(b * 64 + h0 + 2) * TSEQ + tl] = f2b(v2);
        Vt[(size_t)(b * 64 + h0 + 3) * TSEQ + tl] = f2b(v3);
      }
    }
  }
}

// ---------------------------------------------------------------------------
// Kernel 2: per-64-chunk V sums + suffix table (single kernel).
// CSS[b][c][h] = sum_{k >= c*64} V[b][k][h], c = 0..32 (CSS[32] = 0).
// Grid 8 blocks x 1024 thr.
// ---------------------------------------------------------------------------
__global__ __launch_bounds__(1024) void css_kernel(const u16* __restrict__ Vt,
                                                   float* __restrict__ CSS) {
  __shared__ float cs[32][64];
  const int b = blockIdx.x;
  const int t = threadIdx.x;
  const int h = t & 63, cg = t >> 6;
  const u16* vp = Vt + ((size_t)b * 64 + h) * TSEQ + cg * 128;
  float s0 = 0.f, s1 = 0.f;
#pragma unroll
  for (int i = 0; i < 8; i++) {
    const short8 a = *(const short8*)(vp + i * 8);
    s0 += b2f((u16)a[0]) + b2f((u16)a[1]) + b2f((u16)a[2]) + b2f((u16)a[3]) +
          b2f((u16)a[4]) + b2f((u16)a[5]) + b2f((u16)a[6]) + b2f((u16)a[7]);
  }
#pragma unroll
  for (int i = 8; i < 16; i++) {
    const short8 a = *(const short8*)(vp + i * 8);
    s1 += b2f((u16)a[0]) + b2f((u16)a[1]) + b2f((u16)a[2]) + b2f((u16)a[3]) +
          b2f((u16)a[4]) + b2f((u16)a[5]) + b2f((u16)a[6]) + b2f((u16)a[7]);
  }
  cs[cg * 2 + 0][h] = s0;
  cs[cg * 2 + 1][h] = s1;
  __syncthreads();
  if (t < 64) {
    float S = 0.f;
    CSS[((size_t)b * 33 + 32) * 64 + t] = 0.f;
    for (int c = 31; c >= 0; c--) {
      S += cs[c][t];
      CSS[((size_t)b * 33 + c) * 64 + t] = S;
    }
  }
}

// ---------------------------------------------------------------------------
// Kernel 3: MFMA attention (unchanged from r6/r7 — proven).
// ---------------------------------------------------------------------------
#define ISSUE_K(K0A, K1A, KO)                                              \
  do {                                                                     \
    _Pragma("unroll") for (int n = 0; n < 4; n++) {                        \
      const u16* kp_ = Kbb + (size_t)((KO) + n * 16 + li) * HDIM + g * 8;  \
      K0A[n] = *(const bf16x8*)(kp_);                                      \
      K1A[n] = *(const bf16x8*)(kp_ + 32);                                 \
    }                                                                      \
  } while (0)

#define ISSUE_V(KO)                                                        \
  do {                                                                     \
    _Pragma("unroll") for (int n = 0; n < 4; n++) {                        \
      const u16* vp_ = Vtb + (size_t)(n * 16 + li) * TSEQ + (KO) + g * 8;  \
      vf0[n] = *(const bf16x8*)(vp_);                                      \
      vf1[n] = *(const bf16x8*)(vp_ + 32);                                 \
    }                                                                      \
  } while (0)

#define COMPUTE_TILE(K0A, K1A, KO)                                         \
  do {                                                                     \
    f32x4 s_[4];                                                           \
    _Pragma("unroll") for (int n = 0; n < 4; n++) {                        \
      s_[n] = (f32x4)0.f;                                                  \
      s_[n] = __builtin_amdgcn_mfma_f32_16x16x32_bf16(qa[0], K0A[n], s_[n], 0, 0, 0); \
      s_[n] = __builtin_amdgcn_mfma_f32_16x16x32_bf16(qa[1], K1A[n], s_[n], 0, 0, 0); \
    }                                                                      \
    _Pragma("unroll") for (int r = 0; r < 4; r++) {                        \
      const int qi_ = qi0 + r;                                             \
      float p0_ = ((KO) + 0 + li <= qi_) ? exp2f(s_[0][r]) : 1.0f;         \
      float p1_ = ((KO) + 16 + li <= qi_) ? exp2f(s_[1][r]) : 1.0f;        \
      float p2_ = ((KO) + 32 + li <= qi_) ? exp2f(s_[2][r]) : 1.0f;        \
      float p3_ = ((KO) + 48 + li <= qi_) ? exp2f(s_[3][r]) : 1.0f;        \
      zacc[r] += (p0_ + p1_) + (p2_ + p3_);                                \
      sp[w][g * 4 + r][li + 0] = p0_;                                      \
      sp[w][g * 4 + r][li + 16] = p1_;                                     \
      sp[w][g * 4 + r][li + 32] = p2_;                                     \
      sp[w][g * 4 + r][li + 48] = p3_;                                     \
    }                                                                      \
    bf16x8 pa0_, pa1_;                                                     \
    {                                                                      \
      const float* pr_ = &sp[w][li][g * 8];                                \
      const float4 a_ = *(const float4*)(pr_);                             \
      const float4 b_ = *(const float4*)(pr_ + 4);                         \
      pa0_ = (bf16x8){(short)f2b(a_.x), (short)f2b(a_.y), (short)f2b(a_.z),\
                      (short)f2b(a_.w), (short)f2b(b_.x), (short)f2b(b_.y),\
                      (short)f2b(b_.z), (short)f2b(b_.w)};                 \
      const float4 c_ = *(const float4*)(pr_ + 32);                        \
      const float4 d_ = *(const float4*)(pr_ + 36);                        \
      pa1_ = (bf16x8){(short)f2b(c_.x), (short)f2b(c_.y), (short)f2b(c_.z),\
                      (short)f2b(c_.w), (short)f2b(d_.x), (short)f2b(d_.y),\
                      (short)f2b(d_.z), (short)f2b(d_.w)};                 \
    }                                                                      \
    _Pragma("unroll") for (int nt = 0; nt < 4; nt++) {                     \
      oacc[nt] = __builtin_amdgcn_mfma_f32_16x16x32_bf16(pa0_, vf0[nt], oacc[nt], 0, 0, 0); \
      oacc[nt] = __builtin_amdgcn_mfma_f32_16x16x32_bf16(pa1_, vf1[nt], oacc[nt], 0, 0, 0); \
    }                                                                      \
  } while (0)

__global__ __launch_bounds__(256, 2) void attn_mfma(
    const u16* __restrict__ Qb, const u16* __restrict__ Kb,
    const u16* __restrict__ Vt, const float* __restrict__ CSS,
    float* __restrict__ Out) {
  __shared__ float sp[4][16][68];  // wave-private P buffer / merge buffer

  const int tid = threadIdx.x;
  const int w = tid >> 6, l = tid & 63;
  const int g = l >> 4, li = l & 15;

  const int gb = blockIdx.x & 7;    // batch -> XCD pin (bid % 8 round-robin)
  const int j = blockIdx.x >> 3;    // 0..127
  const int gr = 127 - j;           // longest-first
  const int q0 = gr * 16;

  const size_t qbase = ((size_t)gb * TSEQ + q0 + li) * HDIM;
  bf16x8 qa[2];
  qa[0] = *(const bf16x8*)(Qb + qbase + g * 8);
  qa[1] = *(const bf16x8*)(Qb + qbase + g * 8 + 32);

  float zacc[4];
  f32x4 oacc[4];
#pragma unroll
  for (int r = 0; r < 4; r++) zacc[r] = 0.f;
#pragma unroll
  for (int nt = 0; nt < 4; nt++) oacc[nt] = (f32x4)0.f;

  const int qi0 = q0 + g * 4;
  const int nt = gr / 4 + 1;  // tiles for this block's rows
  const u16* Kbb = Kb + (size_t)gb * TSEQ * HDIM;
  const u16* Vtb = Vt + (size_t)gb * 64 * TSEQ;

  bf16x8 kA0[4], kA1[4], kB0[4], kB1[4], vf0[4], vf1[4];

  int kt = w;
  if (kt < nt) {
    ISSUE_K(kA0, kA1, kt * 64);
    while (true) {
      ISSUE_V(kt * 64);
      if (kt + 4 < nt) ISSUE_K(kB0, kB1, (kt + 4) * 64);
      __builtin_amdgcn_sched_barrier(0);
      COMPUTE_TILE(kA0, kA1, kt * 64);
      kt += 4;
      if (kt >= nt) break;
      ISSUE_V(kt * 64);
      if (kt + 4 < nt) ISSUE_K(kA0, kA1, (kt + 4) * 64);
      __builtin_amdgcn_sched_barrier(0);
      COMPUTE_TILE(kB0, kB1, kt * 64);
      kt += 4;
      if (kt >= nt) break;
    }
  }

  // per-row Z: reduce zacc over the 16 li lanes
#pragma unroll
  for (int r = 0; r < 4; r++) {
#pragma unroll
    for (int d = 1; d < 16; d <<= 1) zacc[r] += __shfl_xor(zacc[r], d, 64);
  }

  // publish partials into this wave's own sp region
#pragma unroll
  for (int n = 0; n < 4; n++) {
#pragma unroll
    for (int r = 0; r < 4; r++) sp[w][g * 4 + r][n * 16 + li] = oacc[n][r];
  }
  if (li == 0) {
#pragma unroll
    for (int r = 0; r < 4; r++) sp[w][g * 4 + r][64] = zacc[r];
  }
  __syncthreads();

  // merge 4 wave-partials + tail correction + normalize
  const float tailz = (float)(TSEQ - nt * 64);
  const float tailv = CSS[((size_t)gb * 33 + nt) * 64 + l];
#pragma unroll
  for (int r = 0; r < 4; r++) {
    const int q = w * 4 + r;
    const int qi = q0 + q;
    float a = ((sp[0][q][l] + sp[1][q][l]) + (sp[2][q][l] + sp[3][q][l]));
    float zz = ((sp[0][q][64] + sp[1][q][64]) + (sp[2][q][64] + sp[3][q][64]));
    zz += tailz;
    a += tailv;
    Out[((size_t)gb * TSEQ + qi) * HDIM + l] = a / zz;
  }
}

// ---------------------------------------------------------------------------
extern "C" void kernel_launch(void* const* d_in, const int* in_sizes, int n_in,
                              void* d_out, int out_size, void* d_ws, size_t ws_size,
                              hipStream_t stream) {
  const float* X  = (const float*)d_in[0];
  const float* Wq = (const float*)d_in[1];
  const float* bq = (const float*)d_in[2];
  const float* Wk = (const float*)d_in[3];
  const float* bk = (const float*)d_in[4];
  const float* Wv = (const float*)d_in[5];
  const float* bv = (const float*)d_in[6];
  float* out = (float*)d_out;

  // workspace (~6.9 MB)
  char* ws = (char*)d_ws;
  u16*   Qb  = (u16*)(ws);                   // 2 MB  bf16 [NROW][64] (pre-scaled)
  u16*   Kb  = (u16*)(ws + 2097152);         // 2 MB  bf16 [NROW][64]
  u16*   Vt  = (u16*)(ws + 4194304);         // 2 MB  bf16 [B][64][T]
  u16*   Wt  = (u16*)(ws + 6291456);         // 384 KB bf16 [192][1024]
  float* CSS = (float*)(ws + 6684672);       // 67.6 KB fp32 [B][33][64]

  wt_kernel<<<48, 256, 0, stream>>>(Wq, Wk, Wv, Wt);
  proj_mfma<<<NROW / 32, 256, 0, stream>>>(X, Wt, bq, bk, bv, Qb, Kb, Vt);
  css_kernel<<<NBATCH, 1024, 0, stream>>>(Vt, CSS);
  attn_mfma<<<NROW / 16, 256, 0, stream>>>(Qb, Kb, Vt, CSS, out);
}